// Round 1
// baseline (477.177 us; speedup 1.0000x reference)
//
#include <hip/hip_runtime.h>

#define D_IN 256
#define D_HID 128
#define D_OUTC 16

// ---------------- CSR build (dst-sorted) ----------------
__global__ void k_hist(const int* __restrict__ dst, int E, int* __restrict__ deg) {
  int e = blockIdx.x * blockDim.x + threadIdx.x;
  if (e < E) atomicAdd(&deg[dst[e]], 1);
}

__global__ void k_blocksum(const int* __restrict__ deg, int N, int* __restrict__ bsum) {
  __shared__ int sm[512];
  int i = blockIdx.x * 512 + threadIdx.x;
  sm[threadIdx.x] = (i < N) ? deg[i] : 0;
  __syncthreads();
  for (int off = 256; off > 0; off >>= 1) {
    if (threadIdx.x < off) sm[threadIdx.x] += sm[threadIdx.x + off];
    __syncthreads();
  }
  if (threadIdx.x == 0) bsum[blockIdx.x] = sm[0];
}

__global__ void k_scan_partials(const int* __restrict__ bsum, int nch,
                                int* __restrict__ boff,
                                int* __restrict__ row_ptr, int N, int E) {
  __shared__ int sm[128];
  int t = threadIdx.x;
  int v = (t < nch) ? bsum[t] : 0;
  int x = v;
  sm[t] = x; __syncthreads();
  for (int off = 1; off < 128; off <<= 1) {
    int u = (t >= off) ? sm[t - off] : 0;
    __syncthreads();
    x += u; sm[t] = x; __syncthreads();
  }
  if (t < nch) boff[t] = x - v;   // exclusive block offset
  if (t == 0) row_ptr[N] = E;
}

__global__ void k_scan_final(const int* __restrict__ deg, int N,
                             const int* __restrict__ boff,
                             int* __restrict__ row_ptr, int* __restrict__ cursor) {
  __shared__ int sm[512];
  int t = threadIdx.x;
  int i = blockIdx.x * 512 + t;
  int v = (i < N) ? deg[i] : 0;
  int x = v;
  sm[t] = x; __syncthreads();
  for (int off = 1; off < 512; off <<= 1) {
    int u = (t >= off) ? sm[t - off] : 0;
    __syncthreads();
    x += u; sm[t] = x; __syncthreads();
  }
  if (i < N) {
    int ex = x - v + boff[blockIdx.x];
    row_ptr[i] = ex;
    cursor[i]  = ex;
  }
}

__global__ void k_scatter(const int* __restrict__ src, const int* __restrict__ dst,
                          const float* __restrict__ ew, int E,
                          int* __restrict__ cursor,
                          int* __restrict__ s_srt, float* __restrict__ w_srt) {
  int e = blockIdx.x * blockDim.x + threadIdx.x;
  if (e < E) {
    int d = dst[e];
    int p = atomicAdd(&cursor[d], 1);
    s_srt[p] = src[e];
    w_srt[p] = ew[e];
  }
}

// ---------------- dense GEMM: H[N,128] = X[N,K] @ W[K,128] ----------------
// 32 rows x 128 cols per block, 256 threads, 4x4 micro-tile per thread.
template<int K>
__global__ __launch_bounds__(256) void k_gemm(const float* __restrict__ X,
                                              const float* __restrict__ W,
                                              float* __restrict__ H, int N) {
  __shared__ float xs[K * 36];          // transposed [k][36-padded rows]
  const int t   = threadIdx.x;
  const int cg  = t & 31;               // col group -> cols cg*4..cg*4+3
  const int rg  = t >> 5;               // row group -> rows rg*4..rg*4+3
  const int row0 = blockIdx.x * 32;

  for (int idx = t; idx < 32 * K; idx += 256) {
    int r = idx / K;
    int k = idx - r * K;
    int row = row0 + r;
    xs[k * 36 + r] = (row < N) ? X[(size_t)row * K + k] : 0.f;
  }
  __syncthreads();

  float acc[4][4];
  #pragma unroll
  for (int a = 0; a < 4; ++a)
    #pragma unroll
    for (int b = 0; b < 4; ++b) acc[a][b] = 0.f;

  const float* wp = W + cg * 4;
  #pragma unroll 4
  for (int k = 0; k < K; ++k) {
    float4 wv = *reinterpret_cast<const float4*>(wp + (size_t)k * 128);
    float4 xv = *reinterpret_cast<const float4*>(&xs[k * 36 + rg * 4]);
    float xr[4] = {xv.x, xv.y, xv.z, xv.w};
    float wr[4] = {wv.x, wv.y, wv.z, wv.w};
    #pragma unroll
    for (int a = 0; a < 4; ++a)
      #pragma unroll
      for (int b = 0; b < 4; ++b)
        acc[a][b] += xr[a] * wr[b];
  }

  #pragma unroll
  for (int a = 0; a < 4; ++a) {
    int row = row0 + rg * 4 + a;
    if (row < N) {
      float4 o = make_float4(acc[a][0], acc[a][1], acc[a][2], acc[a][3]);
      *reinterpret_cast<float4*>(&H[(size_t)row * 128 + cg * 4]) = o;
    }
  }
}

// ---------------- aggregation: out[n,:] = sum_e w_e * H[src_e,:] + b ----------------
__global__ void k_agg(const float* __restrict__ H, const int* __restrict__ rptr,
                      const int* __restrict__ ssrt, const float* __restrict__ wsrt,
                      const float* __restrict__ bias, float* __restrict__ out,
                      int relu) {
  int n = blockIdx.x;
  int j = threadIdx.x;
  int p0 = rptr[n], p1 = rptr[n + 1];
  float acc = 0.f;
  for (int p = p0; p < p1; ++p) {
    int   s = ssrt[p];
    float w = wsrt[p];
    acc += H[(size_t)s * 128 + j] * w;
  }
  acc += bias[j];
  if (relu) acc = fmaxf(acc, 0.f);
  out[(size_t)n * 128 + j] = acc;
}

// ---------------- fc + log_softmax ----------------
__global__ void k_fc_lsm(const float* __restrict__ emb, const float* __restrict__ fcw,
                         const float* __restrict__ fcb, float* __restrict__ out, int N) {
  int t = threadIdx.x;
  int node = blockIdx.x * 16 + (t >> 4);
  int c = t & 15;
  if (node >= N) return;
  const float* er = emb + (size_t)node * 128;
  float acc = fcb[c];
  #pragma unroll 8
  for (int k = 0; k < 128; ++k) acc += er[k] * fcw[k * 16 + c];
  float m = acc;
  #pragma unroll
  for (int off = 8; off >= 1; off >>= 1) m = fmaxf(m, __shfl_xor(m, off, 16));
  float e = __expf(acc - m);
  float s = e;
  #pragma unroll
  for (int off = 8; off >= 1; off >>= 1) s += __shfl_xor(s, off, 16);
  out[(size_t)node * 16 + c] = acc - m - __logf(s);
}

extern "C" void kernel_launch(void* const* d_in, const int* in_sizes, int n_in,
                              void* d_out, int out_size, void* d_ws, size_t ws_size,
                              hipStream_t stream) {
  const float* x   = (const float*)d_in[0];
  const float* ew  = (const float*)d_in[1];
  const float* W1  = (const float*)d_in[2];
  const float* b1  = (const float*)d_in[3];
  const float* W2  = (const float*)d_in[4];
  const float* b2  = (const float*)d_in[5];
  const float* W3  = (const float*)d_in[6];
  const float* b3  = (const float*)d_in[7];
  const float* fcw = (const float*)d_in[8];
  const float* fcb = (const float*)d_in[9];
  const int*   ei  = (const int*)d_in[10];

  const int N = in_sizes[0] / D_IN;     // 50000
  const int E = in_sizes[1];            // 625000
  const int* srcI = ei;
  const int* dstI = ei + E;

  char* ws = (char*)d_ws;
  size_t o = 0;
  auto take = [&](size_t b) -> char* {
    char* p = ws + o;
    o += (b + 255) & ~(size_t)255;
    return p;
  };
  float* h0   = (float*)take((size_t)N * 128 * 4);
  float* h1   = (float*)take((size_t)N * 128 * 4);
  int*   deg  = (int*)take((size_t)N * 4);
  int*   rptr = (int*)take((size_t)(N + 1) * 4);
  int*   cur  = (int*)take((size_t)N * 4);
  int*   bsum = (int*)take(4096);
  int*   boff = (int*)take(4096);
  int*   ssrt = (int*)take((size_t)E * 4);
  float* wsrt = (float*)take((size_t)E * 4);
  (void)ws_size; (void)n_in; (void)out_size;

  // CSR build (once; reused by all 3 SpMM layers)
  hipMemsetAsync(deg, 0, (size_t)N * 4, stream);
  int eb  = (E + 255) / 256;
  int nch = (N + 511) / 512;
  k_hist<<<eb, 256, 0, stream>>>(dstI, E, deg);
  k_blocksum<<<nch, 512, 0, stream>>>(deg, N, bsum);
  k_scan_partials<<<1, 128, 0, stream>>>(bsum, nch, boff, rptr, N, E);
  k_scan_final<<<nch, 512, 0, stream>>>(deg, N, boff, rptr, cur);
  k_scatter<<<eb, 256, 0, stream>>>(srcI, dstI, ew, E, cur, ssrt, wsrt);

  float* emb = (float*)d_out;
  float* lsm = emb + (size_t)N * 128;
  int gb = (N + 31) / 32;

  k_gemm<256><<<gb, 256, 0, stream>>>(x,  W1, h0, N);
  k_agg<<<N, 128, 0, stream>>>(h0, rptr, ssrt, wsrt, b1, h1, 1);
  k_gemm<128><<<gb, 256, 0, stream>>>(h1, W2, h0, N);
  k_agg<<<N, 128, 0, stream>>>(h0, rptr, ssrt, wsrt, b2, h1, 1);
  k_gemm<128><<<gb, 256, 0, stream>>>(h1, W3, h0, N);
  k_agg<<<N, 128, 0, stream>>>(h0, rptr, ssrt, wsrt, b3, emb, 0);
  k_fc_lsm<<<(N + 15) / 16, 256, 0, stream>>>(emb, fcw, fcb, lsm, N);
}

// Round 2
// 403.574 us; speedup vs baseline: 1.1824x; 1.1824x over previous
//
#include <hip/hip_runtime.h>

#define D_IN 256
#define D_HID 128

typedef __bf16 bf16;
typedef bf16 bf16x8 __attribute__((ext_vector_type(8)));
typedef bf16 bf16x2 __attribute__((ext_vector_type(2)));
typedef float f32x4 __attribute__((ext_vector_type(4)));

// ---------------- CSR build (dst-sorted) ----------------
__global__ void k_hist(const int* __restrict__ dst, int E, int* __restrict__ deg) {
  int e = blockIdx.x * blockDim.x + threadIdx.x;
  if (e < E) atomicAdd(&deg[dst[e]], 1);
}

__global__ void k_blocksum(const int* __restrict__ deg, int N, int* __restrict__ bsum) {
  __shared__ int sm[512];
  int i = blockIdx.x * 512 + threadIdx.x;
  sm[threadIdx.x] = (i < N) ? deg[i] : 0;
  __syncthreads();
  for (int off = 256; off > 0; off >>= 1) {
    if (threadIdx.x < off) sm[threadIdx.x] += sm[threadIdx.x + off];
    __syncthreads();
  }
  if (threadIdx.x == 0) bsum[blockIdx.x] = sm[0];
}

__global__ void k_scan_partials(const int* __restrict__ bsum, int nch,
                                int* __restrict__ boff,
                                int* __restrict__ row_ptr, int N, int E) {
  __shared__ int sm[128];
  int t = threadIdx.x;
  int v = (t < nch) ? bsum[t] : 0;
  int x = v;
  sm[t] = x; __syncthreads();
  for (int off = 1; off < 128; off <<= 1) {
    int u = (t >= off) ? sm[t - off] : 0;
    __syncthreads();
    x += u; sm[t] = x; __syncthreads();
  }
  if (t < nch) boff[t] = x - v;
  if (t == 0) row_ptr[N] = E;
}

__global__ void k_scan_final(const int* __restrict__ deg, int N,
                             const int* __restrict__ boff,
                             int* __restrict__ row_ptr, int* __restrict__ cursor) {
  __shared__ int sm[512];
  int t = threadIdx.x;
  int i = blockIdx.x * 512 + t;
  int v = (i < N) ? deg[i] : 0;
  int x = v;
  sm[t] = x; __syncthreads();
  for (int off = 1; off < 512; off <<= 1) {
    int u = (t >= off) ? sm[t - off] : 0;
    __syncthreads();
    x += u; sm[t] = x; __syncthreads();
  }
  if (i < N) {
    int ex = x - v + boff[blockIdx.x];
    row_ptr[i] = ex;
    cursor[i]  = ex;
  }
}

__global__ void k_scatter(const int* __restrict__ src, const int* __restrict__ dst,
                          const float* __restrict__ ew, int E,
                          int* __restrict__ cursor,
                          int* __restrict__ s_srt, float* __restrict__ w_srt) {
  int e = blockIdx.x * blockDim.x + threadIdx.x;
  if (e < E) {
    int d = dst[e];
    int p = atomicAdd(&cursor[d], 1);
    s_srt[p] = src[e];
    w_srt[p] = ew[e];
  }
}

// ---------------- W transpose + bf16 convert: Wt[c][k] = W[k][c] ----------------
__global__ void k_cvtw(const float* __restrict__ W, bf16* __restrict__ Wt, int K) {
  int idx = blockIdx.x * blockDim.x + threadIdx.x;
  if (idx >= K * 128) return;
  int c = idx / K;
  int k = idx - c * K;
  Wt[(size_t)c * K + k] = (bf16)W[(size_t)k * 128 + c];
}

// ---------------- MFMA GEMM: H[N,128] = A[N,K] @ W[K,128], bf16 in/out, f32 accum
// 256 threads = 4 waves; each wave owns a 16-row strip x 128 cols (8 col-tiles).
// Fragment layouts (mfma_f32_16x16x32_bf16, learn_hip m89/m91/m92-verified):
//   A: lane l holds A[l&15][kt + 8*(l>>4) + e], e=0..7  (one 16B load)
//   B: lane l holds B[kt + 8*(l>>4) + e][l&15]  -> from Wt[col][k] contiguous
//   D: reg r -> row 4*(l>>4)+r, col l&15
template<int K, bool A_IS_F32>
__global__ __launch_bounds__(256) void k_gemm_mfma(const void* __restrict__ Ain,
                                                   const bf16* __restrict__ Wt,
                                                   bf16* __restrict__ Hb, int N) {
  const int t = threadIdx.x;
  const int wave = t >> 6;
  const int lane = t & 63;
  const int l16 = lane & 15;
  const int g = lane >> 4;                 // 0..3 (k-group)
  const int row0 = blockIdx.x * 64 + wave * 16;
  const int arow = row0 + l16;
  const int arow_c = (arow < N) ? arow : (N - 1);

  f32x4 acc[8];
  #pragma unroll
  for (int ct = 0; ct < 8; ++ct) acc[ct] = f32x4{0.f, 0.f, 0.f, 0.f};

  #pragma unroll 2
  for (int kt = 0; kt < K; kt += 32) {
    bf16x8 a;
    if constexpr (A_IS_F32) {
      const float* Af = (const float*)Ain + (size_t)arow_c * K + kt + g * 8;
      f32x4 f0 = *reinterpret_cast<const f32x4*>(Af);
      f32x4 f1 = *reinterpret_cast<const f32x4*>(Af + 4);
      a[0] = (bf16)f0[0]; a[1] = (bf16)f0[1]; a[2] = (bf16)f0[2]; a[3] = (bf16)f0[3];
      a[4] = (bf16)f1[0]; a[5] = (bf16)f1[1]; a[6] = (bf16)f1[2]; a[7] = (bf16)f1[3];
    } else {
      a = *reinterpret_cast<const bf16x8*>((const bf16*)Ain + (size_t)arow_c * K + kt + g * 8);
    }
    #pragma unroll
    for (int ct = 0; ct < 8; ++ct) {
      bf16x8 b = *reinterpret_cast<const bf16x8*>(Wt + (size_t)(ct * 16 + l16) * K + kt + g * 8);
      acc[ct] = __builtin_amdgcn_mfma_f32_16x16x32_bf16(a, b, acc[ct], 0, 0, 0);
    }
  }

  const int orow = row0 + 4 * g;
  #pragma unroll
  for (int ct = 0; ct < 8; ++ct) {
    #pragma unroll
    for (int r = 0; r < 4; ++r) {
      if (orow + r < N)
        Hb[(size_t)(orow + r) * 128 + ct * 16 + l16] = (bf16)acc[ct][r];
    }
  }
}

// ---------------- aggregation: out[n,:] = sum_e w_e * H[src_e,:] + b ----------------
// one wave per node, 2 cols per lane; MODE 0: relu -> bf16 out; MODE 1: -> f32 out
template<int MODE>
__global__ void k_agg(const bf16* __restrict__ H, const int* __restrict__ rptr,
                      const int* __restrict__ ssrt, const float* __restrict__ wsrt,
                      const float* __restrict__ bias, void* __restrict__ out, int N) {
  int node = blockIdx.x * 4 + (threadIdx.x >> 6);
  int lane = threadIdx.x & 63;
  if (node >= N) return;
  int p0 = rptr[node], p1 = rptr[node + 1];
  float a0 = 0.f, a1 = 0.f;
  for (int p = p0; p < p1; ++p) {
    int s = ssrt[p];
    float w = wsrt[p];
    bf16x2 hv = *reinterpret_cast<const bf16x2*>(H + (size_t)s * 128 + lane * 2);
    a0 += w * (float)hv[0];
    a1 += w * (float)hv[1];
  }
  float2 bv = *reinterpret_cast<const float2*>(bias + lane * 2);
  a0 += bv.x; a1 += bv.y;
  if (MODE == 0) {
    a0 = fmaxf(a0, 0.f); a1 = fmaxf(a1, 0.f);
    bf16x2 o; o[0] = (bf16)a0; o[1] = (bf16)a1;
    *reinterpret_cast<bf16x2*>((bf16*)out + (size_t)node * 128 + lane * 2) = o;
  } else {
    float2 o = make_float2(a0, a1);
    *reinterpret_cast<float2*>((float*)out + (size_t)node * 128 + lane * 2) = o;
  }
}

// ---------------- fc + log_softmax ----------------
__global__ void k_fc_lsm(const float* __restrict__ emb, const float* __restrict__ fcw,
                         const float* __restrict__ fcb, float* __restrict__ out, int N) {
  int t = threadIdx.x;
  int node = blockIdx.x * 16 + (t >> 4);
  int c = t & 15;
  if (node >= N) return;
  const float* er = emb + (size_t)node * 128;
  float acc = fcb[c];
  #pragma unroll 8
  for (int k = 0; k < 128; ++k) acc += er[k] * fcw[k * 16 + c];
  float m = acc;
  #pragma unroll
  for (int off = 8; off >= 1; off >>= 1) m = fmaxf(m, __shfl_xor(m, off, 16));
  float e = __expf(acc - m);
  float s = e;
  #pragma unroll
  for (int off = 8; off >= 1; off >>= 1) s += __shfl_xor(s, off, 16);
  out[(size_t)node * 16 + c] = acc - m - __logf(s);
}

extern "C" void kernel_launch(void* const* d_in, const int* in_sizes, int n_in,
                              void* d_out, int out_size, void* d_ws, size_t ws_size,
                              hipStream_t stream) {
  const float* x   = (const float*)d_in[0];
  const float* ew  = (const float*)d_in[1];
  const float* W1  = (const float*)d_in[2];
  const float* b1  = (const float*)d_in[3];
  const float* W2  = (const float*)d_in[4];
  const float* b2  = (const float*)d_in[5];
  const float* W3  = (const float*)d_in[6];
  const float* b3  = (const float*)d_in[7];
  const float* fcw = (const float*)d_in[8];
  const float* fcb = (const float*)d_in[9];
  const int*   ei  = (const int*)d_in[10];

  const int N = in_sizes[0] / D_IN;     // 50000
  const int E = in_sizes[1];            // 625000
  const int* srcI = ei;
  const int* dstI = ei + E;

  char* ws = (char*)d_ws;
  size_t o = 0;
  auto take = [&](size_t b) -> char* {
    char* p = ws + o;
    o += (b + 255) & ~(size_t)255;
    return p;
  };
  bf16*  hb0  = (bf16*)take((size_t)N * 128 * 2);
  bf16*  hb1  = (bf16*)take((size_t)N * 128 * 2);
  bf16*  Wt1  = (bf16*)take((size_t)D_IN * 128 * 2);
  bf16*  Wt2  = (bf16*)take((size_t)D_HID * 128 * 2);
  bf16*  Wt3  = (bf16*)take((size_t)D_HID * 128 * 2);
  int*   deg  = (int*)take((size_t)N * 4);
  int*   rptr = (int*)take((size_t)(N + 1) * 4);
  int*   cur  = (int*)take((size_t)N * 4);
  int*   bsum = (int*)take(4096);
  int*   boff = (int*)take(4096);
  int*   ssrt = (int*)take((size_t)E * 4);
  float* wsrt = (float*)take((size_t)E * 4);
  (void)ws_size; (void)n_in; (void)out_size;

  // CSR build (once; reused by all 3 SpMM layers)
  hipMemsetAsync(deg, 0, (size_t)N * 4, stream);
  int eb  = (E + 255) / 256;
  int nch = (N + 511) / 512;
  k_hist<<<eb, 256, 0, stream>>>(dstI, E, deg);
  k_blocksum<<<nch, 512, 0, stream>>>(deg, N, bsum);
  k_scan_partials<<<1, 128, 0, stream>>>(bsum, nch, boff, rptr, N, E);
  k_scan_final<<<nch, 512, 0, stream>>>(deg, N, boff, rptr, cur);
  k_scatter<<<eb, 256, 0, stream>>>(srcI, dstI, ew, E, cur, ssrt, wsrt);

  // weight transpose + bf16 convert
  k_cvtw<<<(D_IN * 128 + 255) / 256, 256, 0, stream>>>(W1, Wt1, D_IN);
  k_cvtw<<<(D_HID * 128 + 255) / 256, 256, 0, stream>>>(W2, Wt2, D_HID);
  k_cvtw<<<(D_HID * 128 + 255) / 256, 256, 0, stream>>>(W3, Wt3, D_HID);

  float* emb = (float*)d_out;
  float* lsm = emb + (size_t)N * 128;
  int gb = (N + 63) / 64;
  int ab = (N + 3) / 4;

  k_gemm_mfma<D_IN, true><<<gb, 256, 0, stream>>>(x, Wt1, hb0, N);
  k_agg<0><<<ab, 256, 0, stream>>>(hb0, rptr, ssrt, wsrt, b1, hb1, N);
  k_gemm_mfma<D_HID, false><<<gb, 256, 0, stream>>>(hb1, Wt2, hb0, N);
  k_agg<0><<<ab, 256, 0, stream>>>(hb0, rptr, ssrt, wsrt, b2, hb1, N);
  k_gemm_mfma<D_HID, false><<<gb, 256, 0, stream>>>(hb1, Wt3, hb0, N);
  k_agg<1><<<ab, 256, 0, stream>>>(hb0, rptr, ssrt, wsrt, b3, emb, N);
  k_fc_lsm<<<(N + 15) / 16, 256, 0, stream>>>(emb, fcw, fcb, lsm, N);
}

// Round 3
// 290.158 us; speedup vs baseline: 1.6445x; 1.3909x over previous
//
#include <hip/hip_runtime.h>

#define D_IN 256
#define D_HID 128

typedef __bf16 bf16;
typedef bf16 bf16x8 __attribute__((ext_vector_type(8)));
typedef bf16 bf16x4 __attribute__((ext_vector_type(4)));
typedef float f32x4 __attribute__((ext_vector_type(4)));

// ---------------- CSR build (dst-sorted) ----------------
__global__ void k_hist(const int* __restrict__ dst, int E, int* __restrict__ deg) {
  int e = blockIdx.x * blockDim.x + threadIdx.x;
  if (e < E) atomicAdd(&deg[dst[e]], 1);
}

__global__ void k_blocksum(const int* __restrict__ deg, int N, int* __restrict__ bsum) {
  __shared__ int sm[512];
  int i = blockIdx.x * 512 + threadIdx.x;
  sm[threadIdx.x] = (i < N) ? deg[i] : 0;
  __syncthreads();
  for (int off = 256; off > 0; off >>= 1) {
    if (threadIdx.x < off) sm[threadIdx.x] += sm[threadIdx.x + off];
    __syncthreads();
  }
  if (threadIdx.x == 0) bsum[blockIdx.x] = sm[0];
}

__global__ void k_scan_partials(const int* __restrict__ bsum, int nch,
                                int* __restrict__ boff,
                                int* __restrict__ row_ptr, int N, int E) {
  __shared__ int sm[128];
  int t = threadIdx.x;
  int v = (t < nch) ? bsum[t] : 0;
  int x = v;
  sm[t] = x; __syncthreads();
  for (int off = 1; off < 128; off <<= 1) {
    int u = (t >= off) ? sm[t - off] : 0;
    __syncthreads();
    x += u; sm[t] = x; __syncthreads();
  }
  if (t < nch) boff[t] = x - v;
  if (t == 0) row_ptr[N] = E;
}

__global__ void k_scan_final(const int* __restrict__ deg, int N,
                             const int* __restrict__ boff,
                             int* __restrict__ row_ptr, int* __restrict__ cursor) {
  __shared__ int sm[512];
  int t = threadIdx.x;
  int i = blockIdx.x * 512 + t;
  int v = (i < N) ? deg[i] : 0;
  int x = v;
  sm[t] = x; __syncthreads();
  for (int off = 1; off < 512; off <<= 1) {
    int u = (t >= off) ? sm[t - off] : 0;
    __syncthreads();
    x += u; sm[t] = x; __syncthreads();
  }
  if (i < N) {
    int ex = x - v + boff[blockIdx.x];
    row_ptr[i] = ex;
    cursor[i]  = ex;
  }
}

__global__ void k_scatter(const int* __restrict__ src, const int* __restrict__ dst,
                          const float* __restrict__ ew, int E,
                          int* __restrict__ cursor, int2* __restrict__ esw) {
  int e = blockIdx.x * blockDim.x + threadIdx.x;
  if (e < E) {
    int d = dst[e];
    int p = atomicAdd(&cursor[d], 1);
    esw[p] = make_int2(src[e], __float_as_int(ew[e]));
  }
}

// ---------------- fused W transpose + bf16 convert for all 3 layers ----------------
__global__ void k_cvtw_all(const float* __restrict__ W1, const float* __restrict__ W2,
                           const float* __restrict__ W3, bf16* __restrict__ Wt1,
                           bf16* __restrict__ Wt2, bf16* __restrict__ Wt3) {
  int idx = blockIdx.x * blockDim.x + threadIdx.x;
  if (idx < 32768) {                       // Wt1[c][k], K=256
    int c = idx >> 8, k = idx & 255;
    Wt1[idx] = (bf16)W1[k * 128 + c];
  } else if (idx < 49152) {                // Wt2, K=128
    int r = idx - 32768;
    int c = r >> 7, k = r & 127;
    Wt2[r] = (bf16)W2[k * 128 + c];
  } else if (idx < 65536) {                // Wt3, K=128
    int r = idx - 49152;
    int c = r >> 7, k = r & 127;
    Wt3[r] = (bf16)W3[k * 128 + c];
  }
}

// ---------------- MFMA GEMM: H[N,128] = A[N,K] @ W[K,128], bf16 in/out, f32 accum
template<int K, bool A_IS_F32>
__global__ __launch_bounds__(256) void k_gemm_mfma(const void* __restrict__ Ain,
                                                   const bf16* __restrict__ Wt,
                                                   bf16* __restrict__ Hb, int N) {
  const int t = threadIdx.x;
  const int wave = t >> 6;
  const int lane = t & 63;
  const int l16 = lane & 15;
  const int g = lane >> 4;
  const int row0 = blockIdx.x * 64 + wave * 16;
  const int arow = row0 + l16;
  const int arow_c = (arow < N) ? arow : (N - 1);

  f32x4 acc[8];
  #pragma unroll
  for (int ct = 0; ct < 8; ++ct) acc[ct] = f32x4{0.f, 0.f, 0.f, 0.f};

  #pragma unroll 2
  for (int kt = 0; kt < K; kt += 32) {
    bf16x8 a;
    if constexpr (A_IS_F32) {
      const float* Af = (const float*)Ain + (size_t)arow_c * K + kt + g * 8;
      f32x4 f0 = *reinterpret_cast<const f32x4*>(Af);
      f32x4 f1 = *reinterpret_cast<const f32x4*>(Af + 4);
      a[0] = (bf16)f0[0]; a[1] = (bf16)f0[1]; a[2] = (bf16)f0[2]; a[3] = (bf16)f0[3];
      a[4] = (bf16)f1[0]; a[5] = (bf16)f1[1]; a[6] = (bf16)f1[2]; a[7] = (bf16)f1[3];
    } else {
      a = *reinterpret_cast<const bf16x8*>((const bf16*)Ain + (size_t)arow_c * K + kt + g * 8);
    }
    #pragma unroll
    for (int ct = 0; ct < 8; ++ct) {
      bf16x8 b = *reinterpret_cast<const bf16x8*>(Wt + (size_t)(ct * 16 + l16) * K + kt + g * 8);
      acc[ct] = __builtin_amdgcn_mfma_f32_16x16x32_bf16(a, b, acc[ct], 0, 0, 0);
    }
  }

  const int orow = row0 + 4 * g;
  #pragma unroll
  for (int ct = 0; ct < 8; ++ct) {
    #pragma unroll
    for (int r = 0; r < 4; ++r) {
      if (orow + r < N)
        Hb[(size_t)(orow + r) * 128 + ct * 16 + l16] = (bf16)acc[ct][r];
    }
  }
}

// ---------------- aggregation: out[n,:] = sum_e w_e * H[src_e,:] + b ----------------
// One wave per node. Half-wave edge pairing: lanes 0-31 handle edge p, lanes
// 32-63 edge p+1 (bf16x4 = 8B/lane covers the 256B row per half). 2x unroll ->
// 4 independent row gathers in flight. Packed int2 (src, w) = 1 load/edge.
template<int MODE>
__global__ __launch_bounds__(256) void k_agg(const bf16* __restrict__ H,
                                             const int* __restrict__ rptr,
                                             const int2* __restrict__ esw,
                                             const float* __restrict__ bias,
                                             void* __restrict__ out, int N) {
  const int node = blockIdx.x * 4 + (threadIdx.x >> 6);
  if (node >= N) return;
  const int lane = threadIdx.x & 63;
  const int l31 = lane & 31;
  const int half = lane >> 5;
  const int p1 = rptr[node + 1];
  float a0 = 0.f, a1 = 0.f, a2 = 0.f, a3 = 0.f;
  int p = rptr[node] + half;
  for (; p + 2 < p1; p += 4) {
    int2 e0 = esw[p];
    int2 e1 = esw[p + 2];
    bf16x4 h0 = *reinterpret_cast<const bf16x4*>(H + (size_t)e0.x * 128 + l31 * 4);
    bf16x4 h1 = *reinterpret_cast<const bf16x4*>(H + (size_t)e1.x * 128 + l31 * 4);
    float w0 = __int_as_float(e0.y), w1 = __int_as_float(e1.y);
    a0 += w0 * (float)h0[0] + w1 * (float)h1[0];
    a1 += w0 * (float)h0[1] + w1 * (float)h1[1];
    a2 += w0 * (float)h0[2] + w1 * (float)h1[2];
    a3 += w0 * (float)h0[3] + w1 * (float)h1[3];
  }
  if (p < p1) {
    int2 e0 = esw[p];
    bf16x4 h0 = *reinterpret_cast<const bf16x4*>(H + (size_t)e0.x * 128 + l31 * 4);
    float w0 = __int_as_float(e0.y);
    a0 += w0 * (float)h0[0];
    a1 += w0 * (float)h0[1];
    a2 += w0 * (float)h0[2];
    a3 += w0 * (float)h0[3];
  }
  a0 += __shfl_xor(a0, 32);
  a1 += __shfl_xor(a1, 32);
  a2 += __shfl_xor(a2, 32);
  a3 += __shfl_xor(a3, 32);
  if (half == 0) {
    float4 bv = *reinterpret_cast<const float4*>(bias + l31 * 4);
    a0 += bv.x; a1 += bv.y; a2 += bv.z; a3 += bv.w;
    if (MODE == 0) {
      bf16x4 o;
      o[0] = (bf16)fmaxf(a0, 0.f); o[1] = (bf16)fmaxf(a1, 0.f);
      o[2] = (bf16)fmaxf(a2, 0.f); o[3] = (bf16)fmaxf(a3, 0.f);
      *reinterpret_cast<bf16x4*>((bf16*)out + (size_t)node * 128 + l31 * 4) = o;
    } else {
      f32x4 o = {a0, a1, a2, a3};
      *reinterpret_cast<f32x4*>((float*)out + (size_t)node * 128 + l31 * 4) = o;
    }
  }
}

// ---------------- fc + log_softmax ----------------
__global__ void k_fc_lsm(const float* __restrict__ emb, const float* __restrict__ fcw,
                         const float* __restrict__ fcb, float* __restrict__ out, int N) {
  int t = threadIdx.x;
  int node = blockIdx.x * 16 + (t >> 4);
  int c = t & 15;
  if (node >= N) return;
  const float* er = emb + (size_t)node * 128;
  float acc = fcb[c];
  #pragma unroll 8
  for (int k = 0; k < 128; ++k) acc += er[k] * fcw[k * 16 + c];
  float m = acc;
  #pragma unroll
  for (int off = 8; off >= 1; off >>= 1) m = fmaxf(m, __shfl_xor(m, off, 16));
  float e = __expf(acc - m);
  float s = e;
  #pragma unroll
  for (int off = 8; off >= 1; off >>= 1) s += __shfl_xor(s, off, 16);
  out[(size_t)node * 16 + c] = acc - m - __logf(s);
}

extern "C" void kernel_launch(void* const* d_in, const int* in_sizes, int n_in,
                              void* d_out, int out_size, void* d_ws, size_t ws_size,
                              hipStream_t stream) {
  const float* x   = (const float*)d_in[0];
  const float* ew  = (const float*)d_in[1];
  const float* W1  = (const float*)d_in[2];
  const float* b1  = (const float*)d_in[3];
  const float* W2  = (const float*)d_in[4];
  const float* b2  = (const float*)d_in[5];
  const float* W3  = (const float*)d_in[6];
  const float* b3  = (const float*)d_in[7];
  const float* fcw = (const float*)d_in[8];
  const float* fcb = (const float*)d_in[9];
  const int*   ei  = (const int*)d_in[10];

  const int N = in_sizes[0] / D_IN;     // 50000
  const int E = in_sizes[1];            // 625000
  const int* srcI = ei;
  const int* dstI = ei + E;

  char* ws = (char*)d_ws;
  size_t o = 0;
  auto take = [&](size_t b) -> char* {
    char* p = ws + o;
    o += (b + 255) & ~(size_t)255;
    return p;
  };
  bf16*  hb0  = (bf16*)take((size_t)N * 128 * 2);
  bf16*  hb1  = (bf16*)take((size_t)N * 128 * 2);
  bf16*  Wt1  = (bf16*)take((size_t)D_IN * 128 * 2);
  bf16*  Wt2  = (bf16*)take((size_t)D_HID * 128 * 2);
  bf16*  Wt3  = (bf16*)take((size_t)D_HID * 128 * 2);
  int*   deg  = (int*)take((size_t)N * 4);
  int*   rptr = (int*)take((size_t)(N + 1) * 4);
  int*   cur  = (int*)take((size_t)N * 4);
  int*   bsum = (int*)take(4096);
  int*   boff = (int*)take(4096);
  int2*  esw  = (int2*)take((size_t)E * 8);
  (void)ws_size; (void)n_in; (void)out_size;

  // CSR build (once; reused by all 3 SpMM layers)
  hipMemsetAsync(deg, 0, (size_t)N * 4, stream);
  int eb  = (E + 255) / 256;
  int nch = (N + 511) / 512;
  k_hist<<<eb, 256, 0, stream>>>(dstI, E, deg);
  k_blocksum<<<nch, 512, 0, stream>>>(deg, N, bsum);
  k_scan_partials<<<1, 128, 0, stream>>>(bsum, nch, boff, rptr, N, E);
  k_scan_final<<<nch, 512, 0, stream>>>(deg, N, boff, rptr, cur);
  k_scatter<<<eb, 256, 0, stream>>>(srcI, dstI, ew, E, cur, esw);

  // weight transpose + bf16 convert (fused, one launch)
  k_cvtw_all<<<256, 256, 0, stream>>>(W1, W2, W3, Wt1, Wt2, Wt3);

  float* emb = (float*)d_out;
  float* lsm = emb + (size_t)N * 128;
  int gb = (N + 63) / 64;
  int ab = (N + 3) / 4;

  k_gemm_mfma<D_IN, true><<<gb, 256, 0, stream>>>(x, Wt1, hb0, N);
  k_agg<0><<<ab, 256, 0, stream>>>(hb0, rptr, esw, b1, hb1, N);
  k_gemm_mfma<D_HID, false><<<gb, 256, 0, stream>>>(hb1, Wt2, hb0, N);
  k_agg<0><<<ab, 256, 0, stream>>>(hb0, rptr, esw, b2, hb1, N);
  k_gemm_mfma<D_HID, false><<<gb, 256, 0, stream>>>(hb1, Wt3, hb0, N);
  k_agg<1><<<ab, 256, 0, stream>>>(hb0, rptr, esw, b3, emb, N);
  k_fc_lsm<<<(N + 15) / 16, 256, 0, stream>>>(emb, fcw, fcb, lsm, N);
}

// Round 4
// 253.471 us; speedup vs baseline: 1.8826x; 1.1447x over previous
//
#include <hip/hip_runtime.h>

#define D_IN 256
#define D_HID 128

typedef __bf16 bf16;
typedef bf16 bf16x8 __attribute__((ext_vector_type(8)));
typedef bf16 bf16x4 __attribute__((ext_vector_type(4)));
typedef float f32x4 __attribute__((ext_vector_type(4)));

// ---------------- CSR build (dst-sorted) ----------------
__global__ void k_hist(const int* __restrict__ dst, int E, int* __restrict__ deg) {
  int e = blockIdx.x * blockDim.x + threadIdx.x;
  if (e < E) atomicAdd(&deg[dst[e]], 1);
}

__global__ void k_blocksum(const int* __restrict__ deg, int N, int* __restrict__ bsum) {
  __shared__ int sm[512];
  int i = blockIdx.x * 512 + threadIdx.x;
  sm[threadIdx.x] = (i < N) ? deg[i] : 0;
  __syncthreads();
  for (int off = 256; off > 0; off >>= 1) {
    if (threadIdx.x < off) sm[threadIdx.x] += sm[threadIdx.x + off];
    __syncthreads();
  }
  if (threadIdx.x == 0) bsum[blockIdx.x] = sm[0];
}

__global__ void k_scan_partials(const int* __restrict__ bsum, int nch,
                                int* __restrict__ boff,
                                int* __restrict__ row_ptr, int N, int E) {
  __shared__ int sm[128];
  int t = threadIdx.x;
  int v = (t < nch) ? bsum[t] : 0;
  int x = v;
  sm[t] = x; __syncthreads();
  for (int off = 1; off < 128; off <<= 1) {
    int u = (t >= off) ? sm[t - off] : 0;
    __syncthreads();
    x += u; sm[t] = x; __syncthreads();
  }
  if (t < nch) boff[t] = x - v;
  if (t == 0) row_ptr[N] = E;
}

__global__ void k_scan_final(const int* __restrict__ deg, int N,
                             const int* __restrict__ boff,
                             int* __restrict__ row_ptr, int* __restrict__ cursor) {
  __shared__ int sm[512];
  int t = threadIdx.x;
  int i = blockIdx.x * 512 + t;
  int v = (i < N) ? deg[i] : 0;
  int x = v;
  sm[t] = x; __syncthreads();
  for (int off = 1; off < 512; off <<= 1) {
    int u = (t >= off) ? sm[t - off] : 0;
    __syncthreads();
    x += u; sm[t] = x; __syncthreads();
  }
  if (i < N) {
    int ex = x - v + boff[blockIdx.x];
    row_ptr[i] = ex;
    cursor[i]  = ex;
  }
}

__global__ void k_scatter(const int* __restrict__ src, const int* __restrict__ dst,
                          const float* __restrict__ ew, int E,
                          int* __restrict__ cursor, int2* __restrict__ esw) {
  int e = blockIdx.x * blockDim.x + threadIdx.x;
  if (e < E) {
    int d = dst[e];
    int p = atomicAdd(&cursor[d], 1);
    esw[p] = make_int2(src[e], __float_as_int(ew[e]));
  }
}

// ---------------- pack W -> MFMA-fragment-major bf16 ----------------
// Bpack element r: e = r&7, lane = (r>>3)&63, f = r>>9; ct = f&7, kt = f>>3.
// Bpack[r] = W[kt*32 + 8*(lane>>4) + e][ct*16 + (lane&15)]
__global__ void k_pack_all(const float* __restrict__ W1, const float* __restrict__ W2,
                           const float* __restrict__ W3, bf16* __restrict__ B1,
                           bf16* __restrict__ B2, bf16* __restrict__ B3) {
  int idx = blockIdx.x * blockDim.x + threadIdx.x;
  const float* W; bf16* B; int r;
  if (idx < 32768)      { W = W1; B = B1; r = idx; }
  else if (idx < 49152) { W = W2; B = B2; r = idx - 32768; }
  else if (idx < 65536) { W = W3; B = B3; r = idx - 49152; }
  else return;
  int e = r & 7, l = (r >> 3) & 63, f = r >> 9;
  int ct = f & 7, kt = f >> 3;
  int k = kt * 32 + ((l >> 4) << 3) + e;
  int c = ct * 16 + (l & 15);
  B[r] = (bf16)W[k * 128 + c];
}

// ---------------- MFMA GEMM: H[N,128] = A[N,K] @ W[K,128] ----------------
// 4 waves/block, 16 rows/wave, 128 cols. All A-fragments hoisted to regs;
// B-fragment loads are coalesced 1KB wave loads from Bpack (L2-hot).
template<int K, bool A_IS_F32>
__global__ __launch_bounds__(256) void k_gemm_mfma(const void* __restrict__ Ain,
                                                   const bf16* __restrict__ Bp,
                                                   bf16* __restrict__ Hb, int N) {
  constexpr int NKT = K / 32;
  const int t = threadIdx.x;
  const int wave = t >> 6;
  const int lane = t & 63;
  const int l16 = lane & 15;
  const int g = lane >> 4;
  const int row0 = blockIdx.x * 64 + wave * 16;
  const int arow = row0 + l16;
  const int arow_c = (arow < N) ? arow : (N - 1);

  bf16x8 afr[NKT];
  if constexpr (A_IS_F32) {
    const float* Af = (const float*)Ain + (size_t)arow_c * K + g * 8;
    #pragma unroll
    for (int kt = 0; kt < NKT; ++kt) {
      f32x4 f0 = *reinterpret_cast<const f32x4*>(Af + kt * 32);
      f32x4 f1 = *reinterpret_cast<const f32x4*>(Af + kt * 32 + 4);
      bf16x8 a;
      a[0] = (bf16)f0[0]; a[1] = (bf16)f0[1]; a[2] = (bf16)f0[2]; a[3] = (bf16)f0[3];
      a[4] = (bf16)f1[0]; a[5] = (bf16)f1[1]; a[6] = (bf16)f1[2]; a[7] = (bf16)f1[3];
      afr[kt] = a;
    }
  } else {
    const bf16* Ab = (const bf16*)Ain + (size_t)arow_c * K + g * 8;
    #pragma unroll
    for (int kt = 0; kt < NKT; ++kt)
      afr[kt] = *reinterpret_cast<const bf16x8*>(Ab + kt * 32);
  }

  const bf16x8* Bv = reinterpret_cast<const bf16x8*>(Bp);
  f32x4 acc[8];
  #pragma unroll
  for (int ct = 0; ct < 8; ++ct) acc[ct] = f32x4{0.f, 0.f, 0.f, 0.f};

  #pragma unroll
  for (int kt = 0; kt < NKT; ++kt) {
    #pragma unroll
    for (int ct = 0; ct < 8; ++ct) {
      bf16x8 b = Bv[(size_t)(kt * 8 + ct) * 64 + lane];
      acc[ct] = __builtin_amdgcn_mfma_f32_16x16x32_bf16(afr[kt], b, acc[ct], 0, 0, 0);
    }
  }

  const int orow = row0 + 4 * g;
  #pragma unroll
  for (int ct = 0; ct < 8; ++ct) {
    #pragma unroll
    for (int r = 0; r < 4; ++r) {
      if (orow + r < N)
        Hb[(size_t)(orow + r) * 128 + ct * 16 + l16] = (bf16)acc[ct][r];
    }
  }
}

// ---------------- aggregation: out[n,:] = sum_e w_e * H[src_e,:] + b ----------------
template<int MODE>
__global__ __launch_bounds__(256) void k_agg(const bf16* __restrict__ H,
                                             const int* __restrict__ rptr,
                                             const int2* __restrict__ esw,
                                             const float* __restrict__ bias,
                                             void* __restrict__ out, int N) {
  const int node = blockIdx.x * 4 + (threadIdx.x >> 6);
  if (node >= N) return;
  const int lane = threadIdx.x & 63;
  const int l31 = lane & 31;
  const int half = lane >> 5;
  const int p1 = rptr[node + 1];
  float a0 = 0.f, a1 = 0.f, a2 = 0.f, a3 = 0.f;
  int p = rptr[node] + half;
  for (; p + 2 < p1; p += 4) {
    int2 e0 = esw[p];
    int2 e1 = esw[p + 2];
    bf16x4 h0 = *reinterpret_cast<const bf16x4*>(H + (size_t)e0.x * 128 + l31 * 4);
    bf16x4 h1 = *reinterpret_cast<const bf16x4*>(H + (size_t)e1.x * 128 + l31 * 4);
    float w0 = __int_as_float(e0.y), w1 = __int_as_float(e1.y);
    a0 += w0 * (float)h0[0] + w1 * (float)h1[0];
    a1 += w0 * (float)h0[1] + w1 * (float)h1[1];
    a2 += w0 * (float)h0[2] + w1 * (float)h1[2];
    a3 += w0 * (float)h0[3] + w1 * (float)h1[3];
  }
  if (p < p1) {
    int2 e0 = esw[p];
    bf16x4 h0 = *reinterpret_cast<const bf16x4*>(H + (size_t)e0.x * 128 + l31 * 4);
    float w0 = __int_as_float(e0.y);
    a0 += w0 * (float)h0[0];
    a1 += w0 * (float)h0[1];
    a2 += w0 * (float)h0[2];
    a3 += w0 * (float)h0[3];
  }
  a0 += __shfl_xor(a0, 32);
  a1 += __shfl_xor(a1, 32);
  a2 += __shfl_xor(a2, 32);
  a3 += __shfl_xor(a3, 32);
  if (half == 0) {
    float4 bv = *reinterpret_cast<const float4*>(bias + l31 * 4);
    a0 += bv.x; a1 += bv.y; a2 += bv.z; a3 += bv.w;
    if (MODE == 0) {
      bf16x4 o;
      o[0] = (bf16)fmaxf(a0, 0.f); o[1] = (bf16)fmaxf(a1, 0.f);
      o[2] = (bf16)fmaxf(a2, 0.f); o[3] = (bf16)fmaxf(a3, 0.f);
      *reinterpret_cast<bf16x4*>((bf16*)out + (size_t)node * 128 + l31 * 4) = o;
    } else {
      f32x4 o = {a0, a1, a2, a3};
      *reinterpret_cast<f32x4*>((float*)out + (size_t)node * 128 + l31 * 4) = o;
    }
  }
}

// ---------------- fc + log_softmax ----------------
__global__ void k_fc_lsm(const float* __restrict__ emb, const float* __restrict__ fcw,
                         const float* __restrict__ fcb, float* __restrict__ out, int N) {
  int t = threadIdx.x;
  int node = blockIdx.x * 16 + (t >> 4);
  int c = t & 15;
  if (node >= N) return;
  const float* er = emb + (size_t)node * 128;
  float acc = fcb[c];
  #pragma unroll 8
  for (int k = 0; k < 128; ++k) acc += er[k] * fcw[k * 16 + c];
  float m = acc;
  #pragma unroll
  for (int off = 8; off >= 1; off >>= 1) m = fmaxf(m, __shfl_xor(m, off, 16));
  float e = __expf(acc - m);
  float s = e;
  #pragma unroll
  for (int off = 8; off >= 1; off >>= 1) s += __shfl_xor(s, off, 16);
  out[(size_t)node * 16 + c] = acc - m - __logf(s);
}

extern "C" void kernel_launch(void* const* d_in, const int* in_sizes, int n_in,
                              void* d_out, int out_size, void* d_ws, size_t ws_size,
                              hipStream_t stream) {
  const float* x   = (const float*)d_in[0];
  const float* ew  = (const float*)d_in[1];
  const float* W1  = (const float*)d_in[2];
  const float* b1  = (const float*)d_in[3];
  const float* W2  = (const float*)d_in[4];
  const float* b2  = (const float*)d_in[5];
  const float* W3  = (const float*)d_in[6];
  const float* b3  = (const float*)d_in[7];
  const float* fcw = (const float*)d_in[8];
  const float* fcb = (const float*)d_in[9];
  const int*   ei  = (const int*)d_in[10];

  const int N = in_sizes[0] / D_IN;     // 50000
  const int E = in_sizes[1];            // 625000
  const int* srcI = ei;
  const int* dstI = ei + E;

  char* ws = (char*)d_ws;
  size_t o = 0;
  auto take = [&](size_t b) -> char* {
    char* p = ws + o;
    o += (b + 255) & ~(size_t)255;
    return p;
  };
  bf16*  hb0  = (bf16*)take((size_t)N * 128 * 2);
  bf16*  hb1  = (bf16*)take((size_t)N * 128 * 2);
  bf16*  Bp1  = (bf16*)take((size_t)D_IN * 128 * 2);
  bf16*  Bp2  = (bf16*)take((size_t)D_HID * 128 * 2);
  bf16*  Bp3  = (bf16*)take((size_t)D_HID * 128 * 2);
  int*   deg  = (int*)take((size_t)N * 4);
  int*   rptr = (int*)take((size_t)(N + 1) * 4);
  int*   cur  = (int*)take((size_t)N * 4);
  int*   bsum = (int*)take(4096);
  int*   boff = (int*)take(4096);
  int2*  esw  = (int2*)take((size_t)E * 8);
  (void)ws_size; (void)n_in; (void)out_size;

  // CSR build (once; reused by all 3 SpMM layers)
  hipMemsetAsync(deg, 0, (size_t)N * 4, stream);
  int eb  = (E + 255) / 256;
  int nch = (N + 511) / 512;
  k_hist<<<eb, 256, 0, stream>>>(dstI, E, deg);
  k_blocksum<<<nch, 512, 0, stream>>>(deg, N, bsum);
  k_scan_partials<<<1, 128, 0, stream>>>(bsum, nch, boff, rptr, N, E);
  k_scan_final<<<nch, 512, 0, stream>>>(deg, N, boff, rptr, cur);
  k_scatter<<<eb, 256, 0, stream>>>(srcI, dstI, ew, E, cur, esw);

  // weight pack (fragment-major bf16), one launch
  k_pack_all<<<256, 256, 0, stream>>>(W1, W2, W3, Bp1, Bp2, Bp3);

  float* emb = (float*)d_out;
  float* lsm = emb + (size_t)N * 128;
  int gb = (N + 63) / 64;
  int ab = (N + 3) / 4;

  k_gemm_mfma<D_IN, true><<<gb, 256, 0, stream>>>(x, Bp1, hb0, N);
  k_agg<0><<<ab, 256, 0, stream>>>(hb0, rptr, esw, b1, hb1, N);
  k_gemm_mfma<D_HID, false><<<gb, 256, 0, stream>>>(hb1, Bp2, hb0, N);
  k_agg<0><<<ab, 256, 0, stream>>>(hb0, rptr, esw, b2, hb1, N);
  k_gemm_mfma<D_HID, false><<<gb, 256, 0, stream>>>(hb1, Bp3, hb0, N);
  k_agg<1><<<ab, 256, 0, stream>>>(hb0, rptr, esw, b3, emb, N);
  k_fc_lsm<<<(N + 15) / 16, 256, 0, stream>>>(emb, fcw, fcb, lsm, N);
}